// Round 1
// baseline (584.887 us; speedup 1.0000x reference)
//
#include <hip/hip_runtime.h>

// LSTM RNN_20263655702953 — MI355X (gfx950), round 5.
//
// Reference quirk: hs[:, -1, :] selects BATCH index 511 => single sequential
// LSTM chain (1024 steps, H=64), then (1024,64)@(64,2) projection.
// One workgroup, 4 waves (1/SIMD); wave g owns gate g, lane l owns unit l.
//
// R5 change: h broadcast via WAVE-PRIVATE LDS copy + uniform ds_read_b128.
// R4 used 64 v_readlane/wave/step (VALU->SGPR->VALU forwarding, 40% of issue
// slots, hazard wait-states at batch boundaries). Since every wave computes
// h redundantly anyway, each wave writes h to its OWN hb[gate] buffer and
// reads it back next step with 16 same-address ds_read_b128 (broadcast,
// conflict-free, same-wave in-order => NO extra barrier). The ~130cy first
// LDS return hides under the 64-FMA stream (progressive lgkmcnt); x-part
// FMAs moved to accumulator init so they run while reads are in flight.
// All sched_barrier fences removed — compiler schedules freely again.
// Still exactly ONE barrier per step (gbuf gate exchange, double-buffered).

#define T_LEN 1024
#define BATCH 512
#define HID   64

__device__ __forceinline__ float fast_rcp(float x) {
    return __builtin_amdgcn_rcpf(x);  // v_rcp_f32, ~1e-7 rel err
}
__device__ __forceinline__ float fast_tanh(float x) {
    // 1 - 2/(e^{2x}+1); saturates correctly for |x| large
    return 1.0f - 2.0f * fast_rcp(__expf(2.0f * x) + 1.0f);
}

__global__ __launch_bounds__(256, 1)
void lstm_seq_kernel(const float* __restrict__ x,
                     const float* __restrict__ W_ih,
                     const float* __restrict__ W_hh,
                     const float* __restrict__ b_ih,
                     const float* __restrict__ b_hh,
                     const float* __restrict__ W_fc,
                     const float* __restrict__ b_fc,
                     float* __restrict__ out,
                     float* __restrict__ hist)   // d_ws: 1024*64 floats
{
    __shared__ float xs[2 * T_LEN];         // 8 KB: x[:,511,:]
    __shared__ float gbuf[2][4][HID];       // 2 KB: double-buffered gates [buf][gate][unit]
    __shared__ float hb[4][2][HID];         // 2 KB: per-wave double-buffered h copy
    __shared__ float hring[64 * HID];       // 16 KB: ring of last 64 h (wave 0 only)

    const int tid  = threadIdx.x;
    const int lane = tid & 63;
    const int gate = tid >> 6;              // 0..3 = i,f,g,o ; == wave id
    const int row  = tid;                   // gate row in [0,256)

    // ---- stage x[:,511,:] into LDS (one-time)
    for (int j = 0; j < 4; ++j) {
        int t = tid + j * 256;              // 0..1023
        const float2 v = *(const float2*)(x + (size_t)(t * BATCH + (BATCH - 1)) * 2);
        xs[2 * t]     = v.x;
        xs[2 * t + 1] = v.y;
    }

    // h(t=-1) = 0 in each wave's private copy (own-wave write->read, in order)
    hb[gate][0][lane] = 0.0f;

    // ---- preload this lane's W_hh row (natural order) into VGPRs
    float w[HID];
    {
        const float4* wr = (const float4*)(W_hh + row * HID);
        #pragma unroll
        for (int k = 0; k < HID / 4; ++k) {
            float4 v = wr[k];
            w[4*k+0] = v.x; w[4*k+1] = v.y; w[4*k+2] = v.z; w[4*k+3] = v.w;
        }
    }
    const float bsum = b_ih[row] + b_hh[row];
    const float wi0  = W_ih[row * 2 + 0];
    const float wi1  = W_ih[row * 2 + 1];

    // unified activation constants: sigmoid: 1*rcp(1+e^-x)+0 ; tanh: 2*rcp(1+e^-2x)-1
    const float actA = (gate == 2) ? 2.0f : 1.0f;
    const float actB = (gate == 2) ? -2.0f : -1.0f;
    const float actC = (gate == 2) ? -1.0f : 0.0f;

    float cval = 0.0f;   // lane l holds c[l]

    __syncthreads();

    for (int t = 0; t < T_LEN; ++t) {
        const int buf = t & 1;

        // x-part + bias first: independent of h, runs while h reads in flight
        const float2 xv = *(const float2*)(xs + 2 * t);   // uniform bcast
        float a0 = fmaf(wi0, xv.x, bsum);
        a0 = fmaf(wi1, xv.y, a0);
        float a1 = 0.0f, a2 = 0.0f, a3 = 0.0f;

        // ---- h broadcast: 16 uniform ds_read_b128 from own wave's copy.
        // Same-address across lanes => broadcast, conflict-free, one bank pass.
        const float4* h4p = (const float4*)&hb[gate][buf][0];
        float4 hv[16];
        #pragma unroll
        for (int k = 0; k < 16; ++k) hv[k] = h4p[k];

        // ---- 64-FMA dot product, 4 independent chains
        #pragma unroll
        for (int k = 0; k < 16; ++k) {
            a0 = fmaf(w[4*k+0], hv[k].x, a0);
            a1 = fmaf(w[4*k+1], hv[k].y, a1);
            a2 = fmaf(w[4*k+2], hv[k].z, a2);
            a3 = fmaf(w[4*k+3], hv[k].w, a3);
        }
        const float acc = (a0 + a1) + (a2 + a3);

        // unified activation: one exp + one rcp chain
        const float act = fmaf(actA, fast_rcp(1.0f + __expf(actB * acc)), actC);

        gbuf[buf][gate][lane] = act;        // conflict-free (contiguous per wave)
        __syncthreads();                    // the only per-step barrier

        // ---- update phase (redundant in all 4 waves; keeps c replicated)
        const float gi = gbuf[buf][0][lane];
        const float gf = gbuf[buf][1][lane];
        const float gg = gbuf[buf][2][lane];
        const float go = gbuf[buf][3][lane];
        cval = fmaf(gf, cval, gi * gg);
        const float hval = go * fast_tanh(cval);

        // publish h to own wave's other buffer (no barrier: same-wave order)
        hb[gate][buf ^ 1][lane] = hval;

        // h history: wave 0 owns ring + flush (own data => no barrier;
        // global stores drain off the critical path)
        if (gate == 0) {
            hring[(t & 63) * HID + lane] = hval;
            if ((t & 63) == 63) {
                float4*       dst = (float4*)(hist + (t - 63) * HID);
                const float4* src = (const float4*)hring;
                #pragma unroll
                for (int j = 0; j < 16; ++j)     // 4096 floats, coalesced
                    dst[lane + 64 * j] = src[lane + 64 * j];
            }
        }
    }

    __syncthreads();  // wave0's final flush drained & visible (block fence)

    // ---- projection: out[t,o] = b_fc[o] + dot(W_fc[o,:], hist[t,:])
    #pragma unroll
    for (int j = 0; j < 8; ++j) {
        const int idx = tid + j * 256;      // 0..2047, coalesced stores
        const int t   = idx >> 1;
        const int o   = idx & 1;
        const float4* hv4 = (const float4*)(hist + t * HID);
        const float4* wv  = (const float4*)(W_fc + o * HID);
        float p0 = 0.f, p1 = 0.f, p2 = 0.f, p3 = 0.f;
        #pragma unroll
        for (int k = 0; k < HID / 4; ++k) {
            float4 h4 = hv4[k], w4 = wv[k];
            p0 = fmaf(h4.x, w4.x, p0);
            p1 = fmaf(h4.y, w4.y, p1);
            p2 = fmaf(h4.z, w4.z, p2);
            p3 = fmaf(h4.w, w4.w, p3);
        }
        out[idx] = b_fc[o] + ((p0 + p1) + (p2 + p3));
    }
}

extern "C" void kernel_launch(void* const* d_in, const int* in_sizes, int n_in,
                              void* d_out, int out_size, void* d_ws, size_t ws_size,
                              hipStream_t stream) {
    const float* x    = (const float*)d_in[0];
    const float* W_ih = (const float*)d_in[1];
    const float* W_hh = (const float*)d_in[2];
    const float* b_ih = (const float*)d_in[3];
    const float* b_hh = (const float*)d_in[4];
    const float* W_fc = (const float*)d_in[5];
    const float* b_fc = (const float*)d_in[6];
    float* out  = (float*)d_out;
    float* hist = (float*)d_ws;   // needs 1024*64*4 = 256 KB

    lstm_seq_kernel<<<dim3(1), dim3(256), 0, stream>>>(
        x, W_ih, W_hh, b_ih, b_hh, W_fc, b_fc, out, hist);
}

// Round 2
// 545.568 us; speedup vs baseline: 1.0721x; 1.0721x over previous
//
#include <hip/hip_runtime.h>

// LSTM RNN_20263655702953 — MI355X (gfx950), round 6.
//
// Reference quirk: hs[:, -1, :] selects BATCH index 511 => single sequential
// LSTM chain (1024 steps, H=64), then (1024,64)@(64,2) projection.
// One workgroup, 4 waves (1/SIMD); wave g owns gate g, lane l owns unit l.
//
// R6: HYBRID h-broadcast, informed by R4 (readlane, 425us) vs R5 (LDS, 538us):
//  - R5 proved the step is serial-LATENCY bound, not issue bound (VALUBusy
//    fell 0.190->0.134 yet time rose): its ds_write->ds_read h round-trip
//    (~120cy) sat at the HEAD of the FMA stream, uncovered.
//  - R6 uses readlane (zero latency, 2 batches of 16) for h[0..31] and
//    own-wave LDS broadcast (low issue: 8x uniform ds_read_b128) for
//    h[32..63]. The tail reads are issued at the END of the previous step
//    (same-wave DS is in-order after the hb write, no barrier needed); the
//    ~190cy RL+FMA head stream covers their ~120cy latency completely.
//    Net: -32 readlanes of issue, zero added stall.
//  - Raw barrier (s_waitcnt lgkmcnt(0); s_barrier) instead of __syncthreads:
//    does NOT drain vmcnt, so wave0's hist global stores stay in flight
//    across steps. Final real __syncthreads() before projection drains them.
// Still exactly ONE barrier per step (gbuf gate exchange, double-buffered).

#define T_LEN 1024
#define BATCH 512
#define HID   64

__device__ __forceinline__ float fast_rcp(float x) {
    return __builtin_amdgcn_rcpf(x);  // v_rcp_f32, ~1e-7 rel err
}
__device__ __forceinline__ float fast_tanh(float x) {
    // 1 - 2/(e^{2x}+1); saturates correctly for |x| large
    return 1.0f - 2.0f * fast_rcp(__expf(2.0f * x) + 1.0f);
}
__device__ __forceinline__ void fast_barrier() {
    // LDS-only drain + barrier; deliberately no vmcnt (hist stores in flight)
    asm volatile("s_waitcnt lgkmcnt(0)\n\ts_barrier" ::: "memory");
}

__global__ __launch_bounds__(256, 1)
void lstm_seq_kernel(const float* __restrict__ x,
                     const float* __restrict__ W_ih,
                     const float* __restrict__ W_hh,
                     const float* __restrict__ b_ih,
                     const float* __restrict__ b_hh,
                     const float* __restrict__ W_fc,
                     const float* __restrict__ b_fc,
                     float* __restrict__ out,
                     float* __restrict__ hist)   // d_ws: 1024*64 floats
{
    __shared__ float xs[2 * T_LEN];         // 8 KB: x[:,511,:]
    __shared__ float gbuf[2][4][HID];       // 2 KB: double-buffered gates [buf][gate][unit]
    __shared__ float hb[4][HID];            // 1 KB: per-wave h copy (single buffer:
                                            //   write -> tail-prefetch reads -> next write,
                                            //   all same-wave, DS in-order)
    __shared__ float hring[64 * HID];       // 16 KB: ring of last 64 h (wave 0 only)

    const int tid  = threadIdx.x;
    const int lane = tid & 63;
    const int gate = tid >> 6;              // 0..3 = i,f,g,o ; == wave id
    const int row  = tid;                   // gate row in [0,256)

    // ---- stage x[:,511,:] into LDS (one-time)
    for (int j = 0; j < 4; ++j) {
        int t = tid + j * 256;              // 0..1023
        const float2 v = *(const float2*)(x + (size_t)(t * BATCH + (BATCH - 1)) * 2);
        xs[2 * t]     = v.x;
        xs[2 * t + 1] = v.y;
    }
    hb[gate][lane] = 0.0f;                  // h(-1) = 0 in own wave's copy

    // ---- preload this lane's W_hh row (natural order) into VGPRs
    float w[HID];
    {
        const float4* wr = (const float4*)(W_hh + row * HID);
        #pragma unroll
        for (int k = 0; k < HID / 4; ++k) {
            float4 v = wr[k];
            w[4*k+0] = v.x; w[4*k+1] = v.y; w[4*k+2] = v.z; w[4*k+3] = v.w;
        }
    }
    const float bsum = b_ih[row] + b_hh[row];
    const float wi0  = W_ih[row * 2 + 0];
    const float wi1  = W_ih[row * 2 + 1];

    // unified activation constants: sigmoid: 1*rcp(1+e^-x)+0 ; tanh: 2*rcp(1+e^-2x)-1
    const float actA = (gate == 2) ? 2.0f : 1.0f;
    const float actB = (gate == 2) ? -2.0f : -1.0f;
    const float actC = (gate == 2) ? -1.0f : 0.0f;

    // tail-prefetch h[32..63] for t=0 (own-wave in-order after the init write)
    float4 hv[8];
    {
        const float4* p = (const float4*)&hb[gate][0];
        #pragma unroll
        for (int j = 0; j < 8; ++j) hv[j] = p[8 + j];
    }

    float hval = 0.0f;   // lane l holds h[l]  (replicated in every wave)
    float cval = 0.0f;   // lane l holds c[l]

    __syncthreads();

    for (int t = 0; t < T_LEN; ++t) {
        const int buf = t & 1;
        // x-part load issued early (independent), consumed after FMA stream
        const float2 xv = *(const float2*)(xs + 2 * t);   // uniform bcast
        const int hbits = __float_as_int(hval);

        float a0 = bsum, a1 = 0.0f, a2 = 0.0f, a3 = 0.0f;
        int hsA[16], hsB[16];

        // ---- RL batch 0 (h[0..15])
        #pragma unroll
        for (int k = 0; k < 16; ++k) hsA[k] = __builtin_amdgcn_readlane(hbits, k);
        __builtin_amdgcn_sched_barrier(0);
        // ---- FMA batch 0 + RL batch 1 (h[16..31])
        #pragma unroll
        for (int k = 0; k < 16; k += 4) {
            a0 = fmaf(w[k+0], __int_as_float(hsA[k+0]), a0);
            a1 = fmaf(w[k+1], __int_as_float(hsA[k+1]), a1);
            a2 = fmaf(w[k+2], __int_as_float(hsA[k+2]), a2);
            a3 = fmaf(w[k+3], __int_as_float(hsA[k+3]), a3);
        }
        #pragma unroll
        for (int k = 0; k < 16; ++k) hsB[k] = __builtin_amdgcn_readlane(hbits, 16 + k);
        __builtin_amdgcn_sched_barrier(0);
        // ---- FMA batch 1
        #pragma unroll
        for (int k = 0; k < 16; k += 4) {
            a0 = fmaf(w[16+k+0], __int_as_float(hsB[k+0]), a0);
            a1 = fmaf(w[16+k+1], __int_as_float(hsB[k+1]), a1);
            a2 = fmaf(w[16+k+2], __int_as_float(hsB[k+2]), a2);
            a3 = fmaf(w[16+k+3], __int_as_float(hsB[k+3]), a3);
        }
        __builtin_amdgcn_sched_barrier(0);
        // ---- FMA tail: h[32..63] from prefetched LDS regs (issued last step,
        //      latency long since covered by the RL/FMA head stream)
        #pragma unroll
        for (int j = 0; j < 8; ++j) {
            a0 = fmaf(w[32+4*j+0], hv[j].x, a0);
            a1 = fmaf(w[32+4*j+1], hv[j].y, a1);
            a2 = fmaf(w[32+4*j+2], hv[j].z, a2);
            a3 = fmaf(w[32+4*j+3], hv[j].w, a3);
        }

        // x contribution last (its LDS wait lands here, long since done)
        float acc = ((a0 + a1) + (a2 + a3));
        acc = fmaf(wi0, xv.x, acc);
        acc = fmaf(wi1, xv.y, acc);

        // unified activation: one exp + one rcp chain
        const float act = fmaf(actA, fast_rcp(1.0f + __expf(actB * acc)), actC);

        gbuf[buf][gate][lane] = act;        // conflict-free (contiguous per wave)
        fast_barrier();                     // the only per-step barrier (lgkm-only)

        // ---- update phase (redundant in all 4 waves; keeps h,c replicated)
        const float gi = gbuf[buf][0][lane];
        const float gf = gbuf[buf][1][lane];
        const float gg = gbuf[buf][2][lane];
        const float go = gbuf[buf][3][lane];
        cval = fmaf(gf, cval, gi * gg);
        hval = go * fast_tanh(cval);

        // publish h to own wave's copy, then issue next step's tail prefetch
        // (same-wave DS ops execute in order: reads see the new h)
        hb[gate][lane] = hval;
        {
            const float4* p = (const float4*)&hb[gate][0];
            #pragma unroll
            for (int j = 0; j < 8; ++j) hv[j] = p[8 + j];
        }

        // h history: wave 0 owns ring + flush (own data => no barrier;
        // global stores drain off the critical path — raw barrier skips vmcnt)
        if (gate == 0) {
            hring[(t & 63) * HID + lane] = hval;
            if ((t & 63) == 63) {
                float4*       dst = (float4*)(hist + (t - 63) * HID);
                const float4* src = (const float4*)hring;
                #pragma unroll
                for (int j = 0; j < 16; ++j)     // 4096 floats, coalesced
                    dst[lane + 64 * j] = src[lane + 64 * j];
            }
        }
    }

    __syncthreads();  // true barrier: drains wave0's vmcnt, hist visible

    // ---- projection: out[t,o] = b_fc[o] + dot(W_fc[o,:], hist[t,:])
    #pragma unroll
    for (int j = 0; j < 8; ++j) {
        const int idx = tid + j * 256;      // 0..2047, coalesced stores
        const int t   = idx >> 1;
        const int o   = idx & 1;
        const float4* hv4 = (const float4*)(hist + t * HID);
        const float4* wv  = (const float4*)(W_fc + o * HID);
        float p0 = 0.f, p1 = 0.f, p2 = 0.f, p3 = 0.f;
        #pragma unroll
        for (int k = 0; k < HID / 4; ++k) {
            float4 h4 = hv4[k], w4 = wv[k];
            p0 = fmaf(h4.x, w4.x, p0);
            p1 = fmaf(h4.y, w4.y, p1);
            p2 = fmaf(h4.z, w4.z, p2);
            p3 = fmaf(h4.w, w4.w, p3);
        }
        out[idx] = b_fc[o] + ((p0 + p1) + (p2 + p3));
    }
}

extern "C" void kernel_launch(void* const* d_in, const int* in_sizes, int n_in,
                              void* d_out, int out_size, void* d_ws, size_t ws_size,
                              hipStream_t stream) {
    const float* x    = (const float*)d_in[0];
    const float* W_ih = (const float*)d_in[1];
    const float* W_hh = (const float*)d_in[2];
    const float* b_ih = (const float*)d_in[3];
    const float* b_hh = (const float*)d_in[4];
    const float* W_fc = (const float*)d_in[5];
    const float* b_fc = (const float*)d_in[6];
    float* out  = (float*)d_out;
    float* hist = (float*)d_ws;   // needs 1024*64*4 = 256 KB

    lstm_seq_kernel<<<dim3(1), dim3(256), 0, stream>>>(
        x, W_ih, W_hh, b_ih, b_hh, W_fc, b_fc, out, hist);
}